// Round 2
// baseline (1773.310 us; speedup 1.0000x reference)
//
#include <hip/hip_runtime.h>
#include <hip/hip_bf16.h>
#include <cstddef>

#define NN 1024
#define HH 12
#define SQK 16
#define SV 16
#define PQK 4
#define PV 8
#define C1 384
#define C2 128
#define COUT 384

#define HSQK (HH*SQK)            // 192
#define HKV  (HH*(SQK+SV))       // 384
#define QPF  (HH*3*PQK)          // 144
#define KVPF (HH*3*(PQK+PV))     // 432
#define FDIM (HH*(C2+SV+4*PV))   // 2112

__device__ __constant__ const float SCALAR_W  = 0.14433756729740643f; // 1/sqrt(48)
__device__ __constant__ const float POINT_W   = 0.13608276348795434f; // 1/sqrt(54)
__device__ __constant__ const float W2D_SCALE = 0.5773502691896258f;  // 1/sqrt(3)

// ---------------- workspace layout (float offsets) — identical total to round 1 (69.3 MB)
constexpr size_t OFF_QS     = 0;                        // 1024*192
constexpr size_t OFF_KVS    = OFF_QS     + 196608;      // 1024*384
constexpr size_t OFF_QPF    = OFF_KVS    + 393216;      // 1024*144
constexpr size_t OFF_KVPF   = OFF_QPF    + 147456;      // 1024*432 ; KT2 (344064) aliases here after points_kernel
constexpr size_t OFF_QPTG   = OFF_KVPF   + 442368;      // 1024*144
constexpr size_t OFF_KVPTG  = OFF_QPTG   + 147456;      // 1024*432
constexpr size_t OFF_Q2     = OFF_KVPTG  + 442368;      // 12*1024
constexpr size_t OFF_K2     = OFF_Q2     + 12288;       // 12*1024
constexpr size_t OFF_PW     = OFF_K2     + 12288;       // 64
constexpr size_t OFF_VT     = OFF_PW     + 64;          // 1024*480  [m][480]
constexpr size_t OFF_RESPTG = OFF_VT     + 491520;      // 1024*288
constexpr size_t OFF_FINAL  = OFF_RESPTG + 294912;      // 1024*2112
constexpr size_t OFF_BASE   = OFF_FINAL  + 2162688;     // 12*1024*1024 ; attn aliases base (overwritten in place)

// ---------------- generic 128x64 fp32 GEMM tile (unchanged) ----------------
template <bool ATOMIC>
__device__ void gemm_tile_128x64(const float* __restrict__ A, const float* __restrict__ W,
                                 const float* __restrict__ bias, float* __restrict__ C,
                                 int K, int Ncols, int m0, int n0, int k0, int ktiles,
                                 bool addbias)
{
    __shared__ float As[16][136];
    __shared__ float Bs[16][68];
    const int t  = threadIdx.x;
    const int tx = t & 15;
    const int ty = t >> 4;

    float acc[8][4];
#pragma unroll
    for (int i = 0; i < 8; ++i)
#pragma unroll
        for (int j = 0; j < 4; ++j) acc[i][j] = 0.f;

    for (int kt = 0; kt < ktiles; ++kt) {
        const int kb = k0 + kt * 16;
        {
            const int mi = t >> 1, k8 = (t & 1) * 8;
            const float* src = A + (size_t)(m0 + mi) * K + kb + k8;
            float4 v0 = *(const float4*)(src);
            float4 v1 = *(const float4*)(src + 4);
            As[k8 + 0][mi] = v0.x; As[k8 + 1][mi] = v0.y;
            As[k8 + 2][mi] = v0.z; As[k8 + 3][mi] = v0.w;
            As[k8 + 4][mi] = v1.x; As[k8 + 5][mi] = v1.y;
            As[k8 + 6][mi] = v1.z; As[k8 + 7][mi] = v1.w;
        }
        {
            const int kk = t >> 4, n4 = (t & 15) * 4;
            const int col = n0 + n4;
            float4 v = make_float4(0.f, 0.f, 0.f, 0.f);
            if (col < Ncols) v = *(const float4*)(W + (size_t)(kb + kk) * Ncols + col);
            *(float4*)&Bs[kk][n4] = v;
        }
        __syncthreads();
#pragma unroll
        for (int kk = 0; kk < 16; ++kk) {
            float bv[4];
            *(float4*)bv = *(const float4*)&Bs[kk][tx * 4];
            float av[8];
            *(float4*)&av[0] = *(const float4*)&As[kk][ty * 8];
            *(float4*)&av[4] = *(const float4*)&As[kk][ty * 8 + 4];
#pragma unroll
            for (int i = 0; i < 8; ++i)
#pragma unroll
                for (int j = 0; j < 4; ++j) acc[i][j] += av[i] * bv[j];
        }
        __syncthreads();
    }
#pragma unroll
    for (int i = 0; i < 8; ++i) {
        const int row = m0 + ty * 8 + i;
#pragma unroll
        for (int j = 0; j < 4; ++j) {
            const int col = n0 + tx * 4 + j;
            if (col < Ncols) {
                float v = acc[i][j] + (addbias ? bias[col] : 0.f);
                if (ATOMIC) atomicAdd(&C[(size_t)row * Ncols + col], v);
                else        C[(size_t)row * Ncols + col] = v;
            }
        }
    }
}

// ---------------- 1: fused projection GEMMs (unchanged) ----------------
__global__ __launch_bounds__(256) void proj_kernel(
    const float* __restrict__ A,
    const float* __restrict__ wqs,  const float* __restrict__ bqs,
    const float* __restrict__ wkvs, const float* __restrict__ bkvs,
    const float* __restrict__ wqp,  const float* __restrict__ bqp,
    const float* __restrict__ wkvp, const float* __restrict__ bkvp,
    float* __restrict__ qs, float* __restrict__ kvs,
    float* __restrict__ qpf, float* __restrict__ kvpf)
{
    const int ct = blockIdx.x % 19;
    const int mt = blockIdx.x / 19;
    const float *W, *bias; float* C; int Ncols, n0;
    if (ct < 3)       { W = wqs;  bias = bqs;  C = qs;   Ncols = 192; n0 = ct * 64; }
    else if (ct < 9)  { W = wkvs; bias = bkvs; C = kvs;  Ncols = 384; n0 = (ct - 3) * 64; }
    else if (ct < 12) { W = wqp;  bias = bqp;  C = qpf;  Ncols = 144; n0 = (ct - 9) * 64; }
    else              { W = wkvp; bias = bkvp; C = kvpf; Ncols = 432; n0 = (ct - 12) * 64; }
    gemm_tile_128x64<false>(A, W, bias, C, C1, Ncols, mt * 128, n0, 0, 24, true);
}

// ---------------- 2: point transform, q2/k2, pw (unchanged) ----------------
__global__ __launch_bounds__(192) void points_kernel(
    const float* __restrict__ qpf, const float* __restrict__ kvpf,
    const float* __restrict__ rot, const float* __restrict__ trans,
    const float* __restrict__ tpw,
    float* __restrict__ qptg, float* __restrict__ kvptg,
    float* __restrict__ q2, float* __restrict__ k2, float* __restrict__ pw)
{
    __shared__ float lq[48 * 3];
    __shared__ float lkv[144 * 3];
    const int n = blockIdx.x, t = threadIdx.x;
    float r[9], tr[3];
#pragma unroll
    for (int i = 0; i < 9; ++i) r[i] = rot[n * 9 + i];
#pragma unroll
    for (int i = 0; i < 3; ++i) tr[i] = trans[n * 3 + i];

    if (t < 48) {
        float p0 = qpf[n * QPF + t], p1 = qpf[n * QPF + 48 + t], p2 = qpf[n * QPF + 96 + t];
#pragma unroll
        for (int i = 0; i < 3; ++i)
            lq[t * 3 + i] = r[i * 3 + 0] * p0 + r[i * 3 + 1] * p1 + r[i * 3 + 2] * p2 + tr[i];
    }
    if (t < 144) {
        float p0 = kvpf[(size_t)n * KVPF + t];
        float p1 = kvpf[(size_t)n * KVPF + 144 + t];
        float p2 = kvpf[(size_t)n * KVPF + 288 + t];
#pragma unroll
        for (int i = 0; i < 3; ++i)
            lkv[t * 3 + i] = r[i * 3 + 0] * p0 + r[i * 3 + 1] * p1 + r[i * 3 + 2] * p2 + tr[i];
    }
    __syncthreads();
    if (t < 48) {
#pragma unroll
        for (int i = 0; i < 3; ++i) qptg[(size_t)n * QPF + t * 3 + i] = lq[t * 3 + i];
    }
    if (t < 144) {
#pragma unroll
        for (int i = 0; i < 3; ++i) kvptg[(size_t)n * KVPF + t * 3 + i] = lkv[t * 3 + i];
    }
    if (t < HH) {
        float s = 0.f;
#pragma unroll
        for (int p = 0; p < 4; ++p)
#pragma unroll
            for (int i = 0; i < 3; ++i) { float v = lq[(t * 4 + p) * 3 + i]; s += v * v; }
        q2[t * NN + n] = s;
        float s2 = 0.f;
#pragma unroll
        for (int p = 0; p < 4; ++p)
#pragma unroll
            for (int i = 0; i < 3; ++i) { float v = lkv[(t * 12 + p) * 3 + i]; s2 += v * v; }
        k2[t * NN + n] = s2;
        if (n == 0) {
            float x = tpw[t];
            float sp = (x > 20.f) ? x : log1pf(__expf(x));
            pw[t] = sp * POINT_W;
        }
    }
}

// ---------------- 3: build VT[m][480] and KT2[h*28+f][m] ----------------
__global__ __launch_bounds__(256) void tables_kernel(const float* __restrict__ kvs,
                                                     const float* __restrict__ kvptg,
                                                     float* __restrict__ vT,
                                                     float* __restrict__ kt2)
{
    const int b = blockIdx.x, t = threadIdx.x;
    if (b < NN) {
        const int m = b;
        for (int o = t; o < 480; o += 256) {
            float val;
            if (o < 192) {
                const int h = o >> 4, c = o & 15;
                val = kvs[(size_t)m * HKV + h * 32 + 16 + c];
            } else {
                const int q = o - 192, h = q / 24, j = q % 24;
                val = kvptg[(size_t)m * KVPF + h * 36 + 12 + j];
            }
            vT[(size_t)m * 480 + o] = val;
        }
    } else {
        const int i = (b - NN) * 256 + t;  // < 336*1024
        const int m = i & 1023, hf = i >> 10;
        if (hf < 336) {
            const int h = hf / 28, f = hf % 28;
            float val = (f < 16) ? kvs[(size_t)m * HKV + h * 32 + f]
                                 : kvptg[(size_t)m * KVPF + h * 36 + (f - 16)];
            kt2[(size_t)hf * NN + m] = val;
        }
    }
}

// ---------------- 4: logits base = scalar QK + point QK + mask + b2d ----------------
__global__ __launch_bounds__(256) void qkbase_kernel(
    const float* __restrict__ qs, const float* __restrict__ qptg,
    const float* __restrict__ kt2, const float* __restrict__ q2,
    const float* __restrict__ k2, const float* __restrict__ pw,
    const float* __restrict__ mask, const float* __restrict__ b2d,
    float* __restrict__ base)
{
    __shared__ float qf[8 * 28];
    __shared__ float q2s[8];
    __shared__ float mks[8];
    const int h = blockIdx.x >> 7;        // 12
    const int n0 = (blockIdx.x & 127) * 8;
    const int t = threadIdx.x;
    const float pwh = pw[h];

    if (t < 224) {
        const int ni = t / 28, f = t % 28;
        float v = (f < 16) ? SCALAR_W * qs[(size_t)(n0 + ni) * HSQK + h * 16 + f]
                           : pwh * qptg[(size_t)(n0 + ni) * QPF + h * 12 + (f - 16)];
        qf[t] = v;
    }
    if (t < 8) { q2s[t] = q2[h * NN + n0 + t]; mks[t] = mask[n0 + t]; }
    __syncthreads();

    const int m4 = t * 4;
    float4 acc[8];
#pragma unroll
    for (int ni = 0; ni < 8; ++ni) acc[ni] = make_float4(0.f, 0.f, 0.f, 0.f);

    for (int f = 0; f < 28; ++f) {
        float4 kv = *(const float4*)(kt2 + ((size_t)(h * 28 + f)) * NN + m4);
#pragma unroll
        for (int ni = 0; ni < 8; ++ni) {
            float s = qf[ni * 28 + f];
            acc[ni].x += s * kv.x; acc[ni].y += s * kv.y;
            acc[ni].z += s * kv.z; acc[ni].w += s * kv.w;
        }
    }
    float4 k2v = *(const float4*)(k2 + h * NN + m4);
    float4 mm  = *(const float4*)(mask + m4);
    const float bb = W2D_SCALE * b2d[h];
#pragma unroll
    for (int ni = 0; ni < 8; ++ni) {
        float4 o;
        const float q2n = q2s[ni], mkn = mks[ni];
        o.x = acc[ni].x - 0.5f * pwh * (q2n + k2v.x) + bb - 100000.f * (1.f - mkn * mm.x);
        o.y = acc[ni].y - 0.5f * pwh * (q2n + k2v.y) + bb - 100000.f * (1.f - mkn * mm.y);
        o.z = acc[ni].z - 0.5f * pwh * (q2n + k2v.z) + bb - 100000.f * (1.f - mkn * mm.z);
        o.w = acc[ni].w - 0.5f * pwh * (q2n + k2v.w) + bb - 100000.f * (1.f - mkn * mm.w);
        *(float4*)(base + ((size_t)h * NN + n0 + ni) * NN + m4) = o;
    }
}

// ---------------- 5: fused a2d + softmax (streams inputs_2d once, coalesced) ----
// block per n. thread t: fixed c4 = t&31; wave loads 2 contiguous rows (1 KB) per iter.
__global__ __launch_bounds__(256) void a2dsm_kernel(
    const float* __restrict__ in2d, const float* __restrict__ w2d,
    float* __restrict__ base /* read base, write attn in place */)
{
    __shared__ float lg[12 * 1040];
    __shared__ float ws2[C2 * HH];
    const int n = blockIdx.x, t = threadIdx.x;

    for (int i = t; i < C2 * HH; i += 256) ws2[i] = w2d[i];
    // init lg from base (coalesced global reads)
#pragma unroll
    for (int h = 0; h < HH; ++h) {
        float4 v = *(const float4*)(base + ((size_t)h * NN + n) * NN + 4 * t);
        *(float4*)&lg[h * 1040 + 4 * t] = v;
    }
    __syncthreads();

    const int c4 = t & 31;
    float wreg[4][12];
#pragma unroll
    for (int i = 0; i < 4; ++i)
#pragma unroll
        for (int h = 0; h < HH; ++h)
            wreg[i][h] = W2D_SCALE * ws2[(c4 * 4 + i) * HH + h];

    const int rgrp = t >> 5;            // 0..7
    const int b1 = t & 1, b2 = (t >> 1) & 1;
    const bool writer = ((t & 28) == 0);
    const int hbase = 6 * b1 + 3 * b2;
    const float* src = in2d + ((size_t)n * NN) * C2 + c4 * 4;

    for (int j = 0; j < 128; ++j) {
        const int row = j * 8 + rgrp;
        float4 v = *(const float4*)(src + (size_t)row * C2);
        float part[12];
#pragma unroll
        for (int h = 0; h < HH; ++h)
            part[h] = v.x * wreg[0][h] + v.y * wreg[1][h] + v.z * wreg[2][h] + v.w * wreg[3][h];
        // split butterfly over 32 c-lanes
        float s6[6];
#pragma unroll
        for (int k = 0; k < 6; ++k) {
            float keep = b1 ? part[k + 6] : part[k];
            float give = b1 ? part[k] : part[k + 6];
            s6[k] = keep + __shfl_xor(give, 1);
        }
        float s3[3];
#pragma unroll
        for (int k = 0; k < 3; ++k) {
            float keep = b2 ? s6[k + 3] : s6[k];
            float give = b2 ? s6[k] : s6[k + 3];
            s3[k] = keep + __shfl_xor(give, 2);
        }
#pragma unroll
        for (int k = 0; k < 3; ++k) {
            s3[k] += __shfl_xor(s3[k], 4);
            s3[k] += __shfl_xor(s3[k], 8);
            s3[k] += __shfl_xor(s3[k], 16);
        }
        if (writer) {
#pragma unroll
            for (int k = 0; k < 3; ++k)
                lg[(hbase + k) * 1040 + row] += s3[k];
        }
    }
    __syncthreads();

    // softmax: wave w handles heads 3w..3w+2
    const int w = t >> 6, l = t & 63;
#pragma unroll
    for (int k = 0; k < 3; ++k) {
        const int h = w * 3 + k;
        float e[16];
        float mx = -3.0e38f;
#pragma unroll
        for (int i = 0; i < 16; ++i) { e[i] = lg[h * 1040 + i * 64 + l]; mx = fmaxf(mx, e[i]); }
#pragma unroll
        for (int o = 1; o <= 32; o <<= 1) mx = fmaxf(mx, __shfl_xor(mx, o));
        float s = 0.f;
#pragma unroll
        for (int i = 0; i < 16; ++i) { e[i] = __expf(e[i] - mx); s += e[i]; }
#pragma unroll
        for (int o = 1; o <= 32; o <<= 1) s += __shfl_xor(s, o);
        const float inv = 1.f / s;
        float* dst = base + ((size_t)h * NN + n) * NN;
#pragma unroll
        for (int i = 0; i < 16; ++i) dst[i * 64 + l] = e[i] * inv;
    }
}

// ---------------- 6: attn_2d — second inputs_2d pass, fixed-c4 streaming -------
__global__ __launch_bounds__(256) void attn2d_kernel(
    const float* __restrict__ attn, const float* __restrict__ in2d, float* __restrict__ fin)
{
    __shared__ float sh[13200]; // P[12][1040] (12480 f) then reduce buf [8][12][132]
    const int n = blockIdx.x, t = threadIdx.x;
#pragma unroll
    for (int h = 0; h < HH; ++h) {
        float4 v = *(const float4*)(attn + ((size_t)h * NN + n) * NN + 4 * t);
        *(float4*)&sh[h * 1040 + 4 * t] = v;
    }
    __syncthreads();

    const int c4 = t & 31, rgrp = t >> 5;
    float acc[12][4];
#pragma unroll
    for (int h = 0; h < HH; ++h)
#pragma unroll
        for (int i = 0; i < 4; ++i) acc[h][i] = 0.f;

    const float* src = in2d + ((size_t)n * NN) * C2 + c4 * 4;
    for (int j = 0; j < 128; ++j) {
        const int row = j * 8 + rgrp;
        float4 v = *(const float4*)(src + (size_t)row * C2);
        float p[12];
#pragma unroll
        for (int h = 0; h < HH; ++h) p[h] = sh[h * 1040 + row];
#pragma unroll
        for (int h = 0; h < HH; ++h) {
            acc[h][0] += p[h] * v.x; acc[h][1] += p[h] * v.y;
            acc[h][2] += p[h] * v.z; acc[h][3] += p[h] * v.w;
        }
    }
    __syncthreads();
    // stage per-thread partials: buf[(g*12+h)*132 + c4*4 ..]
#pragma unroll
    for (int h = 0; h < HH; ++h)
        *(float4*)&sh[(rgrp * 12 + h) * 132 + c4 * 4] = *(float4*)&acc[h][0];
    __syncthreads();
#pragma unroll
    for (int u = 0; u < 6; ++u) {
        const int o = t + 256 * u;     // < 1536
        const int h = o >> 7, c = o & 127;
        float s = 0.f;
#pragma unroll
        for (int g = 0; g < 8; ++g) s += sh[(g * 12 + h) * 132 + c];
        fin[(size_t)n * FDIM + 576 + o] = s;
    }
}

// ---------------- 7: attn @ V via [m][480] table, output-contiguous lanes ------
__global__ __launch_bounds__(256) void attnv_kernel(
    const float* __restrict__ attn, const float* __restrict__ vT,
    float* __restrict__ fin, float* __restrict__ resptg)
{
    __shared__ float p17[NN * 17]; // [m][17]
    const int n = blockIdx.x, t = threadIdx.x;
#pragma unroll
    for (int h = 0; h < HH; ++h) {
        float4 v = *(const float4*)(attn + ((size_t)h * NN + n) * NN + 4 * t);
        p17[(4 * t + 0) * 17 + h] = v.x;
        p17[(4 * t + 1) * 17 + h] = v.y;
        p17[(4 * t + 2) * 17 + h] = v.z;
        p17[(4 * t + 3) * 17 + h] = v.w;
    }
    __syncthreads();

    const int o1 = t;
    const int o2 = 256 + t;
    const int h1 = (o1 < 192) ? (o1 >> 4) : (o1 - 192) / 24;
    const int h2 = (o2 - 192) / 24;
    const bool has2 = (t < 224);
    float a1 = 0.f, a2 = 0.f;
    for (int m = 0; m < NN; ++m) {
        const float* vr = vT + (size_t)m * 480;
        a1 += p17[m * 17 + h1] * vr[o1];
        if (has2) a2 += p17[m * 17 + h2] * vr[o2];
    }
    if (o1 < 192) fin[(size_t)n * FDIM + o1] = a1;
    else          resptg[(size_t)n * 288 + (o1 - 192)] = a1;
    if (has2)     resptg[(size_t)n * 288 + (o2 - 192)] = a2;
}

// ---------------- 8: invert point transform, dist (unchanged) ----------------
__global__ __launch_bounds__(128) void ptout_kernel(
    const float* __restrict__ resptg, const float* __restrict__ rot,
    const float* __restrict__ trans, float* __restrict__ fin)
{
    const int n = blockIdx.x, t = threadIdx.x;
    if (t >= 96) return;
    float g0 = resptg[(size_t)n * 288 + t * 3 + 0];
    float g1 = resptg[(size_t)n * 288 + t * 3 + 1];
    float g2 = resptg[(size_t)n * 288 + t * 3 + 2];
    float d0 = g0 - trans[n * 3 + 0];
    float d1 = g1 - trans[n * 3 + 1];
    float d2 = g2 - trans[n * 3 + 2];
    float l0 = rot[n * 9 + 0] * d0 + rot[n * 9 + 3] * d1 + rot[n * 9 + 6] * d2;
    float l1 = rot[n * 9 + 1] * d0 + rot[n * 9 + 4] * d1 + rot[n * 9 + 7] * d2;
    float l2 = rot[n * 9 + 2] * d0 + rot[n * 9 + 5] * d1 + rot[n * 9 + 8] * d2;
    const size_t base = (size_t)n * FDIM;
    fin[base + 192 + t] = l0;
    fin[base + 288 + t] = l1;
    fin[base + 384 + t] = l2;
    fin[base + 480 + t] = sqrtf(1e-8f + l0 * l0 + l1 * l1 + l2 * l2);
}

// ---------------- 9: final GEMM (unchanged) ----------------
__global__ __launch_bounds__(256) void outgemm_kernel(
    const float* __restrict__ fin, const float* __restrict__ wout,
    const float* __restrict__ bout, float* __restrict__ out)
{
    const int n0 = blockIdx.x * 64;
    const int m0 = blockIdx.y * 128;
    const int z  = blockIdx.z;
    gemm_tile_128x64<true>(fin, wout, bout, out, FDIM, COUT, m0, n0, z * 352, 22, z == 0);
}

extern "C" void kernel_launch(void* const* d_in, const int* in_sizes, int n_in,
                              void* d_out, int out_size, void* d_ws, size_t ws_size,
                              hipStream_t stream)
{
    const float* in1d  = (const float*)d_in[0];
    const float* in2d  = (const float*)d_in[1];
    const float* mask  = (const float*)d_in[2];
    const float* rot   = (const float*)d_in[3];
    const float* trans = (const float*)d_in[4];
    const float* wqs   = (const float*)d_in[5];
    const float* bqs   = (const float*)d_in[6];
    const float* wkvs  = (const float*)d_in[7];
    const float* bkvs  = (const float*)d_in[8];
    const float* wqp   = (const float*)d_in[9];
    const float* bqp   = (const float*)d_in[10];
    const float* wkvp  = (const float*)d_in[11];
    const float* bkvp  = (const float*)d_in[12];
    const float* w2d   = (const float*)d_in[13];
    const float* b2d   = (const float*)d_in[14];
    const float* tpw   = (const float*)d_in[15];
    const float* wout  = (const float*)d_in[16];
    const float* bout  = (const float*)d_in[17];

    float* ws     = (float*)d_ws;
    float* qs     = ws + OFF_QS;
    float* kvs    = ws + OFF_KVS;
    float* qpf    = ws + OFF_QPF;
    float* kvpf   = ws + OFF_KVPF;
    float* kt2    = ws + OFF_KVPF;   // alias: kvpf dead after points_kernel
    float* qptg   = ws + OFF_QPTG;
    float* kvptg  = ws + OFF_KVPTG;
    float* q2     = ws + OFF_Q2;
    float* k2     = ws + OFF_K2;
    float* pw     = ws + OFF_PW;
    float* vT     = ws + OFF_VT;
    float* resptg = ws + OFF_RESPTG;
    float* fin    = ws + OFF_FINAL;
    float* base   = ws + OFF_BASE;   // logits base, then attn in place

    hipMemsetAsync(d_out, 0, (size_t)out_size * sizeof(float), stream);

    proj_kernel<<<152, 256, 0, stream>>>(in1d, wqs, bqs, wkvs, bkvs, wqp, bqp, wkvp, bkvp,
                                         qs, kvs, qpf, kvpf);
    points_kernel<<<NN, 192, 0, stream>>>(qpf, kvpf, rot, trans, tpw, qptg, kvptg, q2, k2, pw);
    tables_kernel<<<NN + 1344, 256, 0, stream>>>(kvs, kvptg, vT, kt2);
    qkbase_kernel<<<12 * 128, 256, 0, stream>>>(qs, qptg, kt2, q2, k2, pw, mask, b2d, base);
    a2dsm_kernel<<<NN, 256, 0, stream>>>(in2d, w2d, base);
    attn2d_kernel<<<NN, 256, 0, stream>>>(base, in2d, fin);
    attnv_kernel<<<NN, 256, 0, stream>>>(base, vT, fin, resptg);
    ptout_kernel<<<NN, 128, 0, stream>>>(resptg, rot, trans, fin);
    outgemm_kernel<<<dim3(6, 8, 6), 256, 0, stream>>>(fin, wout, bout, (float*)d_out);
}